// Round 1
// baseline (118.546 us; speedup 1.0000x reference)
//
#include <hip/hip_runtime.h>
#include <hip/hip_bf16.h>
#include <stdint.h>

// AttentionBlock: GroupNorm -> 1x1 conv QKV -> 8-head attention (L=1024, D=64)
//                 -> 1x1 conv proj -> residual add.
// B=8, C=512, L=1024. All heavy math in bf16 MFMA (16x16x32) with f32 accum.

#define NB 8
#define NC 512
#define NL 1024
#define NHD 8
#define ND 64

typedef __attribute__((ext_vector_type(4))) float f32x4;
typedef __attribute__((ext_vector_type(8))) short bf16x8;       // MFMA A/B operand
typedef __attribute__((ext_vector_type(4))) unsigned short u16x4;
typedef __attribute__((ext_vector_type(8))) unsigned short u16x8;

#define MFMA16(a, b, c) __builtin_amdgcn_mfma_f32_16x16x32_bf16((a), (b), (c), 0, 0, 0)

static __device__ __forceinline__ unsigned short f2bf(float f) {
  union { float f; uint32_t u; } v; v.f = f;
  uint32_t r = v.u + 0x7fffu + ((v.u >> 16) & 1u);   // round-to-nearest-even
  return (unsigned short)(r >> 16);
}

static __device__ __forceinline__ void gl_lds16(const unsigned short* g, unsigned short* l) {
  // 16B per lane, LDS dest = wave-uniform base + lane*16 (m104 semantics)
  __builtin_amdgcn_global_load_lds(
      (const __attribute__((address_space(1))) void*)g,
      (__attribute__((address_space(3))) void*)l, 16, 0, 0);
}

// ---------------- K0: weights f32 -> bf16 ----------------
__global__ __launch_bounds__(256) void k_conv_w(const float* __restrict__ qkvw,
                                                const float* __restrict__ pw,
                                                unsigned short* __restrict__ qwb,
                                                unsigned short* __restrict__ pwb) {
  int i = blockIdx.x * 256 + threadIdx.x;
  const int NQ4 = (3 * NC * NC) / 4;  // 196608 float4 in qkv_w
  if (i < NQ4) {
    f32x4 v = ((const f32x4*)qkvw)[i];
    u16x4 o; o.x = f2bf(v.x); o.y = f2bf(v.y); o.z = f2bf(v.z); o.w = f2bf(v.w);
    ((u16x4*)qwb)[i] = o;
  } else {
    int j = i - NQ4;                  // < 65536 float4 in proj_w
    f32x4 v = ((const f32x4*)pw)[j];
    u16x4 o; o.x = f2bf(v.x); o.y = f2bf(v.y); o.z = f2bf(v.z); o.w = f2bf(v.w);
    ((u16x4*)pwb)[j] = o;
  }
}

// ---------------- K1: GroupNorm -> xn_t[b][l][c] bf16 ----------------
// One block per (batch, group): 16 channels x 1024. Thread t owns l in [4t,4t+4)
// for all 16 channels (r == channel offset), so it can emit full 32B row chunks.
__global__ __launch_bounds__(256) void k_gnorm(const float* __restrict__ x,
                                               const float* __restrict__ nw,
                                               const float* __restrict__ nb,
                                               unsigned short* __restrict__ xnt) {
  const int b = blockIdx.x >> 5, g = blockIdx.x & 31;
  const float* base = x + ((size_t)b * NC + g * 16) * NL;
  const int t = threadIdx.x;
  f32x4 vals[16];
  float s = 0.f, ss = 0.f;
#pragma unroll
  for (int r = 0; r < 16; ++r) {
    f32x4 v = ((const f32x4*)base)[t + 256 * r];
    vals[r] = v;
    s += v.x + v.y + v.z + v.w;
    ss += v.x * v.x + v.y * v.y + v.z * v.z + v.w * v.w;
  }
#pragma unroll
  for (int m = 1; m < 64; m <<= 1) { s += __shfl_xor(s, m, 64); ss += __shfl_xor(ss, m, 64); }
  __shared__ float red[8];
  const int w = t >> 6;
  if ((t & 63) == 0) { red[w] = s; red[4 + w] = ss; }
  __syncthreads();
  s  = red[0] + red[1] + red[2] + red[3];
  ss = red[4] + red[5] + red[6] + red[7];
  const float mean = s * (1.f / 16384.f);
  const float var  = ss * (1.f / 16384.f) - mean * mean;
  const float inv  = rsqrtf(var + 1e-5f);
  u16x8 ov[4][2];
#pragma unroll
  for (int r = 0; r < 16; ++r) {
    float wcv = nw[g * 16 + r] * inv;
    float bcv = nb[g * 16 + r] - mean * wcv;
    f32x4 v = vals[r];
    ov[0][r >> 3][r & 7] = f2bf(v.x * wcv + bcv);
    ov[1][r >> 3][r & 7] = f2bf(v.y * wcv + bcv);
    ov[2][r >> 3][r & 7] = f2bf(v.z * wcv + bcv);
    ov[3][r >> 3][r & 7] = f2bf(v.w * wcv + bcv);
  }
#pragma unroll
  for (int j = 0; j < 4; ++j) {
    size_t off = ((size_t)b * NL + 4 * t + j) * NC + g * 16;
    *(u16x8*)(xnt + off)     = ov[j][0];
    *(u16x8*)(xnt + off + 8) = ov[j][1];
  }
}

// ---------------- K2: QKV GEMM ----------------
// C[l][o] = sum_c xn_t[l][c] * qkv_w[o][c]; M=1024(l) N=1536(o) K=512(c), per batch.
// 128x128 tile, BK=64, 4 waves (2x2), 4x4 fragments each. Epilogue fuses bias
// (+ q/k scale) and scatters to q[bh][l][ch], k[bh][l][ch], v[bh][ch][l] bf16.
__global__ __launch_bounds__(256) void k_qkv(const unsigned short* __restrict__ xnt,
                                             const unsigned short* __restrict__ qwb,
                                             const float* __restrict__ qkvb,
                                             unsigned short* __restrict__ qt,
                                             unsigned short* __restrict__ kt,
                                             unsigned short* __restrict__ vt) {
  __shared__ __align__(16) unsigned short As[128 * 64];
  __shared__ __align__(16) unsigned short Bs[128 * 64];
  const int m0 = blockIdx.x * 128;  // l
  const int n0 = blockIdx.y * 128;  // o
  const int b = blockIdx.z;
  const int tid = threadIdx.x, lane = tid & 63, w = tid >> 6;
  const int wr = w >> 1, wc = w & 1;
  const unsigned short* Ab = xnt + (size_t)b * NL * NC;

  f32x4 acc[4][4];
#pragma unroll
  for (int mi = 0; mi < 4; ++mi)
#pragma unroll
    for (int ni = 0; ni < 4; ++ni) acc[mi][ni] = (f32x4){0.f, 0.f, 0.f, 0.f};

  for (int k0 = 0; k0 < NC; k0 += 64) {
    // stage A/B tiles: 128 rows x 128B, chunk-XOR swizzle (chunk ^= row&7), linear LDS dest
#pragma unroll
    for (int r = 0; r < 4; ++r) {
      int c = (r * 4 + w) * 64 + lane;
      int row = c >> 3, lc = (c & 7) ^ (row & 7);
      gl_lds16(Ab + (size_t)(m0 + row) * NC + k0 + lc * 8, &As[(r * 4 + w) * 512]);
    }
#pragma unroll
    for (int r = 0; r < 4; ++r) {
      int c = (r * 4 + w) * 64 + lane;
      int row = c >> 3, lc = (c & 7) ^ (row & 7);
      gl_lds16(qwb + (size_t)(n0 + row) * NC + k0 + lc * 8, &Bs[(r * 4 + w) * 512]);
    }
    __syncthreads();
#pragma unroll
    for (int ks = 0; ks < 2; ++ks) {
      bf16x8 af[4], bfr[4];
#pragma unroll
      for (int mi = 0; mi < 4; ++mi) {
        int row = wr * 64 + mi * 16 + (lane & 15);
        int ph = ((lane >> 4) + ks * 4) ^ (row & 7);
        af[mi] = *(const bf16x8*)&As[row * 64 + ph * 8];
      }
#pragma unroll
      for (int ni = 0; ni < 4; ++ni) {
        int row = wc * 64 + ni * 16 + (lane & 15);
        int ph = ((lane >> 4) + ks * 4) ^ (row & 7);
        bfr[ni] = *(const bf16x8*)&Bs[row * 64 + ph * 8];
      }
#pragma unroll
      for (int mi = 0; mi < 4; ++mi)
#pragma unroll
        for (int ni = 0; ni < 4; ++ni)
          acc[mi][ni] = MFMA16(af[mi], bfr[ni], acc[mi][ni]);
    }
    __syncthreads();
  }
  // epilogue: o -> (head, type, ch); 16-wide col blocks never straddle a 64-block
#pragma unroll
  for (int ni = 0; ni < 4; ++ni) {
    int o = n0 + wc * 64 + ni * 16 + (lane & 15);
    int head = o / 192, rem = o - head * 192;
    int type = rem >> 6, ch = rem & 63;
    float bias = qkvb[o];
#pragma unroll
    for (int mi = 0; mi < 4; ++mi) {
      int l0 = m0 + wr * 64 + mi * 16 + ((lane >> 4) << 2);
      if (type == 2) {
        u16x4 pk;
#pragma unroll
        for (int i = 0; i < 4; ++i) pk[i] = f2bf(acc[mi][ni][i] + bias);
        *(u16x4*)&vt[((size_t)(b * NHD + head) * ND + ch) * NL + l0] = pk;
      } else {
        unsigned short* dst =
            (type == 0 ? qt : kt) + ((size_t)(b * NHD + head) * NL + l0) * ND + ch;
#pragma unroll
        for (int i = 0; i < 4; ++i)
          dst[i * ND] = f2bf((acc[mi][ni][i] + bias) * 0.35355339059327373f);
      }
    }
  }
}

// ---------------- K3: flash attention ----------------
// One block per (head-batch, 64-row t-tile); 4 waves x 16 t-rows. K/V tiles (64x64)
// staged in LDS with chunk-XOR swizzle. Online softmax in f32; P rounded to bf16
// through per-wave LDS rows for the PV A-operand.
__global__ __launch_bounds__(256) void k_attn(const unsigned short* __restrict__ qt,
                                              const unsigned short* __restrict__ kt,
                                              const unsigned short* __restrict__ vt,
                                              unsigned short* __restrict__ abuf) {
  __shared__ __align__(16) unsigned short Ks[64 * 64];
  __shared__ __align__(16) unsigned short Vs[64 * 64];
  __shared__ __align__(16) unsigned short Ps[64 * 64];
  const int bh = blockIdx.x >> 4, tb = blockIdx.x & 15;
  const int tid = threadIdx.x, lane = tid & 63, w = tid >> 6;
  const int t0 = tb * 64;
  const unsigned short* qb = qt + (size_t)bh * NL * ND;
  const unsigned short* kb = kt + (size_t)bh * NL * ND;
  const unsigned short* vb = vt + (size_t)bh * ND * NL;

  bf16x8 qf[2];
  {
    int tq = t0 + w * 16 + (lane & 15);
#pragma unroll
    for (int ks = 0; ks < 2; ++ks)
      qf[ks] = *(const bf16x8*)&qb[(size_t)tq * ND + ks * 32 + (lane >> 4) * 8];
  }
  f32x4 pv[4];
#pragma unroll
  for (int ni = 0; ni < 4; ++ni) pv[ni] = (f32x4){0.f, 0.f, 0.f, 0.f};
  float mrun[4], lrun[4];
#pragma unroll
  for (int i = 0; i < 4; ++i) { mrun[i] = -3.0e38f; lrun[i] = 0.f; }

  for (int s0 = 0; s0 < NL; s0 += 64) {
#pragma unroll
    for (int r = 0; r < 2; ++r) {
      int c = (r * 4 + w) * 64 + lane;
      int row = c >> 3, lc = (c & 7) ^ (row & 7);
      gl_lds16(kb + (size_t)(s0 + row) * ND + lc * 8, &Ks[(r * 4 + w) * 512]);
    }
#pragma unroll
    for (int r = 0; r < 2; ++r) {
      int c = (r * 4 + w) * 64 + lane;
      int row = c >> 3, lc = (c & 7) ^ (row & 7);
      gl_lds16(vb + (size_t)row * NL + s0 + lc * 8, &Vs[(r * 4 + w) * 512]);
    }
    __syncthreads();
    // S = q k^T : rows = wave's 16 t, cols = 64 s
    f32x4 sacc[4];
#pragma unroll
    for (int ni = 0; ni < 4; ++ni) sacc[ni] = (f32x4){0.f, 0.f, 0.f, 0.f};
#pragma unroll
    for (int ks = 0; ks < 2; ++ks)
#pragma unroll
      for (int ni = 0; ni < 4; ++ni) {
        int row = ni * 16 + (lane & 15);
        int ph = ((lane >> 4) + ks * 4) ^ (row & 7);
        bf16x8 kf = *(const bf16x8*)&Ks[row * 64 + ph * 8];
        sacc[ni] = MFMA16(qf[ks], kf, sacc[ni]);
      }
    // online softmax: row i lives at t=(lane>>4)*4+i; cols spread over 16-lane group
    float tmax[4], tsum[4], mnew[4], alpha[4], p[4][4];
#pragma unroll
    for (int i = 0; i < 4; ++i)
      tmax[i] = fmaxf(fmaxf(sacc[0][i], sacc[1][i]), fmaxf(sacc[2][i], sacc[3][i]));
#pragma unroll
    for (int m = 1; m < 16; m <<= 1)
#pragma unroll
      for (int i = 0; i < 4; ++i) tmax[i] = fmaxf(tmax[i], __shfl_xor(tmax[i], m, 16));
#pragma unroll
    for (int i = 0; i < 4; ++i) {
      mnew[i] = fmaxf(mrun[i], tmax[i]);
      alpha[i] = __expf(mrun[i] - mnew[i]);
      mrun[i] = mnew[i];
      tsum[i] = 0.f;
    }
#pragma unroll
    for (int ni = 0; ni < 4; ++ni)
#pragma unroll
      for (int i = 0; i < 4; ++i) {
        p[ni][i] = __expf(sacc[ni][i] - mnew[i]);
        tsum[i] += p[ni][i];
      }
#pragma unroll
    for (int m = 1; m < 16; m <<= 1)
#pragma unroll
      for (int i = 0; i < 4; ++i) tsum[i] += __shfl_xor(tsum[i], m, 16);
#pragma unroll
    for (int i = 0; i < 4; ++i) lrun[i] = lrun[i] * alpha[i] + tsum[i];
    // P -> LDS (bf16, swizzled); each wave owns rows [w*16, w*16+16)
#pragma unroll
    for (int ni = 0; ni < 4; ++ni)
#pragma unroll
      for (int i = 0; i < 4; ++i) {
        int tl = w * 16 + ((lane >> 4) << 2) + i;
        int sc = ni * 16 + (lane & 15);
        int ph = (sc >> 3) ^ (tl & 7);
        Ps[tl * 64 + ph * 8 + (sc & 7)] = f2bf(p[ni][i]);
      }
#pragma unroll
    for (int ni = 0; ni < 4; ++ni)
#pragma unroll
      for (int i = 0; i < 4; ++i) pv[ni][i] *= alpha[i];
    asm volatile("s_waitcnt lgkmcnt(0)" ::: "memory");
    // PV: A = P[t][s] (own rows), B^T = Vs[c][s]
#pragma unroll
    for (int ks = 0; ks < 2; ++ks) {
      int trow = w * 16 + (lane & 15);
      int php = ((lane >> 4) + ks * 4) ^ (trow & 7);
      bf16x8 pf = *(const bf16x8*)&Ps[trow * 64 + php * 8];
#pragma unroll
      for (int ni = 0; ni < 4; ++ni) {
        int vrow = ni * 16 + (lane & 15);
        int ph = ((lane >> 4) + ks * 4) ^ (vrow & 7);
        bf16x8 vf = *(const bf16x8*)&Vs[vrow * 64 + ph * 8];
        pv[ni] = MFMA16(pf, vf, pv[ni]);
      }
    }
    __syncthreads();
  }
  // epilogue: a[bh][t][c] bf16
#pragma unroll
  for (int ni = 0; ni < 4; ++ni)
#pragma unroll
    for (int i = 0; i < 4; ++i) {
      int tl = t0 + w * 16 + ((lane >> 4) << 2) + i;
      int cc = ni * 16 + (lane & 15);
      abuf[((size_t)bh * NL + tl) * ND + cc] = f2bf(pv[ni][i] / lrun[i]);
    }
}

// ---------------- K4: proj GEMM + bias + residual ----------------
// C[o][l] = sum_c proj_w[o][c] * a[l][c]; M=512(o) N=1024(l) K=512(c), per batch.
__global__ __launch_bounds__(256) void k_proj(const unsigned short* __restrict__ abuf,
                                              const unsigned short* __restrict__ pwb,
                                              const float* __restrict__ pb,
                                              const float* __restrict__ x,
                                              float* __restrict__ out) {
  __shared__ __align__(16) unsigned short As[128 * 64];
  __shared__ __align__(16) unsigned short Bs[128 * 64];
  const int m0 = blockIdx.x * 128;  // o
  const int n0 = blockIdx.y * 128;  // l
  const int b = blockIdx.z;
  const int tid = threadIdx.x, lane = tid & 63, w = tid >> 6;
  const int wr = w >> 1, wc = w & 1;

  f32x4 acc[4][4];
#pragma unroll
  for (int mi = 0; mi < 4; ++mi)
#pragma unroll
    for (int ni = 0; ni < 4; ++ni) acc[mi][ni] = (f32x4){0.f, 0.f, 0.f, 0.f};

  for (int k0 = 0; k0 < NC; k0 += 64) {
    const int head = k0 >> 6;  // BK=64 tile sits inside one head's 64 channels
#pragma unroll
    for (int r = 0; r < 4; ++r) {
      int c = (r * 4 + w) * 64 + lane;
      int row = c >> 3, lc = (c & 7) ^ (row & 7);
      gl_lds16(pwb + (size_t)(m0 + row) * NC + k0 + lc * 8, &As[(r * 4 + w) * 512]);
    }
#pragma unroll
    for (int r = 0; r < 4; ++r) {
      int c = (r * 4 + w) * 64 + lane;
      int row = c >> 3, lc = (c & 7) ^ (row & 7);
      gl_lds16(abuf + ((size_t)(b * NHD + head) * NL + n0 + row) * ND + lc * 8,
               &Bs[(r * 4 + w) * 512]);
    }
    __syncthreads();
#pragma unroll
    for (int ks = 0; ks < 2; ++ks) {
      bf16x8 af[4], bfr[4];
#pragma unroll
      for (int mi = 0; mi < 4; ++mi) {
        int row = wr * 64 + mi * 16 + (lane & 15);
        int ph = ((lane >> 4) + ks * 4) ^ (row & 7);
        af[mi] = *(const bf16x8*)&As[row * 64 + ph * 8];
      }
#pragma unroll
      for (int ni = 0; ni < 4; ++ni) {
        int row = wc * 64 + ni * 16 + (lane & 15);
        int ph = ((lane >> 4) + ks * 4) ^ (row & 7);
        bfr[ni] = *(const bf16x8*)&Bs[row * 64 + ph * 8];
      }
#pragma unroll
      for (int mi = 0; mi < 4; ++mi)
#pragma unroll
        for (int ni = 0; ni < 4; ++ni)
          acc[mi][ni] = MFMA16(af[mi], bfr[ni], acc[mi][ni]);
    }
    __syncthreads();
  }
#pragma unroll
  for (int mi = 0; mi < 4; ++mi)
#pragma unroll
    for (int i = 0; i < 4; ++i) {
      int o = m0 + wr * 64 + mi * 16 + ((lane >> 4) << 2) + i;
      float pbv = pb[o];
#pragma unroll
      for (int ni = 0; ni < 4; ++ni) {
        int l = n0 + wc * 64 + ni * 16 + (lane & 15);
        size_t idx = ((size_t)b * NC + o) * NL + l;
        out[idx] = x[idx] + acc[mi][ni][i] + pbv;
      }
    }
}

extern "C" void kernel_launch(void* const* d_in, const int* in_sizes, int n_in,
                              void* d_out, int out_size, void* d_ws, size_t ws_size,
                              hipStream_t stream) {
  const float* x    = (const float*)d_in[0];
  const float* nw   = (const float*)d_in[1];
  const float* nb   = (const float*)d_in[2];
  const float* qkvw = (const float*)d_in[3];
  const float* qkvb = (const float*)d_in[4];
  const float* pw   = (const float*)d_in[5];
  const float* pb   = (const float*)d_in[6];
  float* out = (float*)d_out;

  char* ws = (char*)d_ws;
  // xn_t (8.39MB) is dead after k_qkv; abuf overlays it. Total ws use: 35,651,584 B.
  unsigned short* xnt  = (unsigned short*)(ws);
  unsigned short* abuf = (unsigned short*)(ws);             // overlay
  unsigned short* qwb  = (unsigned short*)(ws + 8388608);
  unsigned short* pwb  = (unsigned short*)(ws + 9961472);
  unsigned short* qt   = (unsigned short*)(ws + 10485760);
  unsigned short* kt   = (unsigned short*)(ws + 18874368);
  unsigned short* vt   = (unsigned short*)(ws + 27262976);

  k_conv_w<<<1024, 256, 0, stream>>>(qkvw, pw, qwb, pwb);
  k_gnorm<<<256, 256, 0, stream>>>(x, nw, nb, xnt);
  k_qkv<<<dim3(8, 12, 8), 256, 0, stream>>>(xnt, qwb, qkvb, qt, kt, vt);
  k_attn<<<1024, 256, 0, stream>>>(qt, kt, vt, abuf);
  k_proj<<<dim3(4, 8, 8), 256, 0, stream>>>(abuf, pwb, pb, x, out);
}